// Round 1
// baseline (1125.364 us; speedup 1.0000x reference)
//
#include <hip/hip_runtime.h>
#include <math.h>

#define B_SZ   4
#define T_SEQ  4096
#define E_DIM  512
#define H_DIM  64

#define QTILE  64
#define KTILE  64
#define KSTR   68   // LDS row stride (floats): odd*4 → conflict-free 4-row access, 16B-aligned rows

// ---------------- QKV projection ----------------
// grid: B*T/4 blocks, 256 threads. Each block computes 4 rows of q,k,v.
__global__ __launch_bounds__(256) void qkv_proj(
    const float* __restrict__ x,
    const float* __restrict__ Wq, const float* __restrict__ bq,
    const float* __restrict__ Wk, const float* __restrict__ bk,
    const float* __restrict__ Wv, const float* __restrict__ bv,
    float* __restrict__ q, float* __restrict__ k, float* __restrict__ v)
{
    __shared__ float xs[4 * E_DIM];
    const int t = threadIdx.x;
    const long long row0 = (long long)blockIdx.x * 4;

    // stage 4 rows of x (2048 floats = 512 float4)
    const float4* xsrc = (const float4*)(x + row0 * E_DIM);
    float4* xdst = (float4*)xs;
    xdst[t]       = xsrc[t];
    xdst[t + 256] = xsrc[t + 256];
    __syncthreads();

    const int r = t >> 6;   // row within block
    const int j = t & 63;   // output dim
    float aq = bq[j], ak = bk[j], av = bv[j];
    const float* xr = &xs[r * E_DIM];
    for (int e = 0; e < E_DIM; ++e) {
        const float xv = xr[e];
        aq = fmaf(xv, Wq[e * H_DIM + j], aq);
        ak = fmaf(xv, Wk[e * H_DIM + j], ak);
        av = fmaf(xv, Wv[e * H_DIM + j], av);
    }
    const long long o = (row0 + r) * H_DIM + j;
    q[o] = aq * 0.125f;   // fold softmax scale 1/sqrt(64) into q
    k[o] = ak;
    v[o] = av;
}

// ---------------- causal flash attention ----------------
// grid: B * (T/QTILE) = 256 blocks, 256 threads.
// thread t: q-row qr = t>>2, key-group kg = t&3 (16 keys per tile).
__global__ __launch_bounds__(256) void flash_attn(
    const float* __restrict__ q, const float* __restrict__ k,
    const float* __restrict__ v, float* __restrict__ out)
{
    __shared__ float Ks[KTILE * KSTR];
    __shared__ float Vs[KTILE * KSTR];

    const int t = threadIdx.x;
    const int ntiles = T_SEQ / QTILE;                // 64
    const int b  = blockIdx.x / ntiles;
    const int qt = blockIdx.x % ntiles;
    const int qr = t >> 2;
    const int kg = t & 3;
    const long long qglob = (long long)qt * QTILE + qr;

    // load q row into registers (statically indexed)
    float qreg[H_DIM];
    {
        const float4* qrow = (const float4*)(q + ((long long)b * T_SEQ + qglob) * H_DIM);
        #pragma unroll
        for (int d4 = 0; d4 < 16; ++d4) {
            const float4 qv = qrow[d4];
            qreg[4*d4+0] = qv.x; qreg[4*d4+1] = qv.y;
            qreg[4*d4+2] = qv.z; qreg[4*d4+3] = qv.w;
        }
    }

    float o[H_DIM];
    #pragma unroll
    for (int d = 0; d < H_DIM; ++d) o[d] = 0.f;
    float m = -INFINITY, l = 0.f;

    const float* kbase = k + (long long)b * T_SEQ * H_DIM;
    const float* vbase = v + (long long)b * T_SEQ * H_DIM;

    for (int kt = 0; kt <= qt; ++kt) {
        __syncthreads();   // protect LDS from previous iteration's readers
        // stage K,V tile: 64 rows x 64 floats (1024 float4, 4 per thread)
        {
            const float4* ksrc = (const float4*)(kbase + (long long)kt * KTILE * H_DIM);
            const float4* vsrc = (const float4*)(vbase + (long long)kt * KTILE * H_DIM);
            #pragma unroll
            for (int c = 0; c < 4; ++c) {
                const int fid = t + 256 * c;       // 0..1023
                const int rr = fid >> 4, dd = fid & 15;
                *(float4*)&Ks[rr * KSTR + dd * 4] = ksrc[fid];
                *(float4*)&Vs[rr * KSTR + dd * 4] = vsrc[fid];
            }
        }
        __syncthreads();

        // scores for this thread's 16 keys (kk = 4*i + kg)
        float s[16];
        #pragma unroll
        for (int i = 0; i < 16; ++i) {
            const int kk = 4 * i + kg;
            const float4* krow = (const float4*)&Ks[kk * KSTR];
            float acc = 0.f;
            #pragma unroll
            for (int d4 = 0; d4 < 16; ++d4) {
                const float4 kv = krow[d4];
                acc = fmaf(qreg[4*d4+0], kv.x, acc);
                acc = fmaf(qreg[4*d4+1], kv.y, acc);
                acc = fmaf(qreg[4*d4+2], kv.z, acc);
                acc = fmaf(qreg[4*d4+3], kv.w, acc);
            }
            s[i] = acc;
        }
        if (kt == qt) {   // diagonal tile: causal mask
            #pragma unroll
            for (int i = 0; i < 16; ++i) {
                const int kk = 4 * i + kg;
                if ((long long)kt * KTILE + kk > qglob) s[i] = -INFINITY;
            }
        }

        // online softmax (state shared across the 4 lanes of a q-row group)
        float tm = s[0];
        #pragma unroll
        for (int i = 1; i < 16; ++i) tm = fmaxf(tm, s[i]);
        tm = fmaxf(tm, __shfl_xor(tm, 1));
        tm = fmaxf(tm, __shfl_xor(tm, 2));
        const float mn = fmaxf(m, tm);
        const float alpha = __expf(m - mn);
        m = mn;

        float p[16];
        float ps = 0.f;
        #pragma unroll
        for (int i = 0; i < 16; ++i) { p[i] = __expf(s[i] - mn); ps += p[i]; }
        l = l * alpha + ps;

        #pragma unroll
        for (int d = 0; d < H_DIM; ++d) o[d] *= alpha;

        #pragma unroll
        for (int i = 0; i < 16; ++i) {
            const int kk = 4 * i + kg;
            const float4* vrow = (const float4*)&Vs[kk * KSTR];
            const float pi = p[i];
            #pragma unroll
            for (int d4 = 0; d4 < 16; ++d4) {
                const float4 vv = vrow[d4];
                o[4*d4+0] = fmaf(pi, vv.x, o[4*d4+0]);
                o[4*d4+1] = fmaf(pi, vv.y, o[4*d4+1]);
                o[4*d4+2] = fmaf(pi, vv.z, o[4*d4+2]);
                o[4*d4+3] = fmaf(pi, vv.w, o[4*d4+3]);
            }
        }
    }

    // combine the 4 partial accumulators of each q-row group
    #pragma unroll
    for (int d = 0; d < H_DIM; ++d) {
        o[d] += __shfl_xor(o[d], 1);
        o[d] += __shfl_xor(o[d], 2);
    }
    l += __shfl_xor(l, 1);
    l += __shfl_xor(l, 2);
    const float inv = 1.f / l;

    // LDS bounce for coalesced output write (reuse Ks)
    __syncthreads();
    if (kg == 0) {
        #pragma unroll
        for (int d = 0; d < H_DIM; ++d) Ks[qr * KSTR + d] = o[d] * inv;
    }
    __syncthreads();
    float4* obase = (float4*)(out + ((long long)b * T_SEQ + (long long)qt * QTILE) * H_DIM);
    #pragma unroll
    for (int c = 0; c < 4; ++c) {
        const int fid = t + 256 * c;
        const int rr = fid >> 4, dd = fid & 15;
        obase[fid] = *(const float4*)&Ks[rr * KSTR + dd * 4];
    }
}

extern "C" void kernel_launch(void* const* d_in, const int* in_sizes, int n_in,
                              void* d_out, int out_size, void* d_ws, size_t ws_size,
                              hipStream_t stream) {
    const float* x  = (const float*)d_in[0];
    const float* Wq = (const float*)d_in[1];
    const float* bq = (const float*)d_in[2];
    const float* Wk = (const float*)d_in[3];
    const float* bk = (const float*)d_in[4];
    const float* Wv = (const float*)d_in[5];
    const float* bv = (const float*)d_in[6];
    float* outp = (float*)d_out;

    const long long rows = (long long)B_SZ * T_SEQ;   // 16384
    float* qb = (float*)d_ws;
    float* kb = qb + rows * H_DIM;
    float* vb = kb + rows * H_DIM;

    qkv_proj<<<dim3(rows / 4), dim3(256), 0, stream>>>(x, Wq, bq, Wk, bk, Wv, bv, qb, kb, vb);
    flash_attn<<<dim3(B_SZ * (T_SEQ / QTILE)), dim3(256), 0, stream>>>(qb, kb, vb, outp);
}

// Round 2
// 255.587 us; speedup vs baseline: 4.4031x; 4.4031x over previous
//
#include <hip/hip_runtime.h>
#include <math.h>

#define B_SZ   4
#define T_SEQ  4096
#define E_DIM  512
#define H_DIM  64
#define NQ     (T_SEQ / 16)   // 256 q-tiles of 16 rows per batch

typedef float f32x4 __attribute__((ext_vector_type(4)));
typedef short s16x4 __attribute__((ext_vector_type(4)));
typedef short s16x8 __attribute__((ext_vector_type(8)));

static __device__ __forceinline__ unsigned short f2bf(float f) {
    union { float f; unsigned int u; } c; c.f = f;
    return (unsigned short)((c.u + 0x7fffu + ((c.u >> 16) & 1u)) >> 16);
}

static __device__ __forceinline__ s16x8 ld_frag(const unsigned short* p0, const unsigned short* p1) {
    s16x4 a = *(const s16x4*)p0;
    s16x4 b = *(const s16x4*)p1;
    return __builtin_shufflevector(a, b, 0, 1, 2, 3, 4, 5, 6, 7);
}

// ---------------- QKV projection: fp32 x @ W -> bf16 q(,scaled), k, and V^T ----------------
// grid: B*T/16 blocks, 256 threads. Wave w handles rows rg*4..rg*4+3 (rg uniform per wave).
__global__ __launch_bounds__(256) void qkv_proj(
    const float* __restrict__ x,
    const float* __restrict__ Wq, const float* __restrict__ bq,
    const float* __restrict__ Wk, const float* __restrict__ bk,
    const float* __restrict__ Wv, const float* __restrict__ bv,
    unsigned short* __restrict__ qo, unsigned short* __restrict__ ko,
    unsigned short* __restrict__ vTo)
{
    const int t  = threadIdx.x;
    const int h  = t & 63;
    const int rg = t >> 6;
    const long long row0 = (long long)blockIdx.x * 16 + (long long)rg * 4;
    const int b    = (int)(row0 >> 12);
    const int tloc = (int)(row0 & 4095);

    float aq[4], ak[4], av[4];
    const float bqh = bq[h], bkh = bk[h], bvh = bv[h];
    #pragma unroll
    for (int r = 0; r < 4; ++r) { aq[r] = bqh; ak[r] = bkh; av[r] = bvh; }

    const float* xr = x + row0 * E_DIM;
    for (int e = 0; e < E_DIM; e += 4) {
        f32x4 xv[4];
        #pragma unroll
        for (int r = 0; r < 4; ++r) xv[r] = *(const f32x4*)(xr + r * E_DIM + e);
        #pragma unroll
        for (int u = 0; u < 4; ++u) {
            const float wq = Wq[(e + u) * H_DIM + h];
            const float wk = Wk[(e + u) * H_DIM + h];
            const float wv = Wv[(e + u) * H_DIM + h];
            #pragma unroll
            for (int r = 0; r < 4; ++r) {
                aq[r] = fmaf(xv[r][u], wq, aq[r]);
                ak[r] = fmaf(xv[r][u], wk, ak[r]);
                av[r] = fmaf(xv[r][u], wv, av[r]);
            }
        }
    }

    #pragma unroll
    for (int r = 0; r < 4; ++r) {
        qo[(row0 + r) * H_DIM + h] = f2bf(aq[r] * 0.125f);  // fold 1/sqrt(64) into q
        ko[(row0 + r) * H_DIM + h] = f2bf(ak[r]);
    }
    s16x4 vv;
    #pragma unroll
    for (int r = 0; r < 4; ++r) vv[r] = (short)f2bf(av[r]);
    *(s16x4*)(vTo + ((long long)(b * H_DIM + h)) * T_SEQ + tloc) = vv;  // V^T [b][h][t]
}

// ---------------- causal flash attention, bf16 MFMA ----------------
// grid: B*NQ = 1024 blocks, 256 threads = 4 waves. All 4 waves share one 16-row
// q-tile; wave w processes k-tiles kt ≡ w (mod 4) (split-K), merged via LDS.
// MFMA k-bijection sigma(g,j) = 4g + (j&3) + 16*(j>>2), used consistently for
// both operands of every MFMA (K-permutation symmetry => layout-guess-free).
// QK^T: S^T = mfma(K, Q)  -> lane l holds S[q=l&15][key=16ks+4g+reg]
// PV:   O^T = mfma(V^T, P^T) -> lane l holds O[q=l&15][h=16hc+4g+reg]
__global__ __launch_bounds__(256, 4) void attn(
    const unsigned short* __restrict__ qb,
    const unsigned short* __restrict__ kb,
    const unsigned short* __restrict__ vT,
    float* __restrict__ out)
{
    __shared__ float Osh[4][64][16];
    __shared__ float msh[4][16];
    __shared__ float lsh[4][16];

    const int t   = threadIdx.x;
    const int wv  = t >> 6;
    const int l   = t & 63;
    const int l15 = l & 15;
    const int g   = l >> 4;

    const int bid = blockIdx.x;
    const int b   = bid & 3;
    const int qi  = (NQ - 1) - (bid >> 2);   // longest q-tiles launch first
    const int q0  = qi * 16;
    const int adiag = (q0 + 15) >> 6;        // index of the (only) masked k-tile

    const unsigned short* kbase = kb + (long long)b * T_SEQ * H_DIM;
    const unsigned short* vbase = vT + (long long)b * H_DIM * T_SEQ;

    // Q fragments (B-operand): lane l holds Q[q0+l15][sigma(g,j)+32*hc]
    const unsigned short* qrow = qb + ((long long)b * T_SEQ + q0 + l15) * H_DIM;
    s16x8 Qf[2];
    #pragma unroll
    for (int hc = 0; hc < 2; ++hc)
        Qf[hc] = ld_frag(qrow + 4 * g + 32 * hc, qrow + 4 * g + 16 + 32 * hc);

    f32x4 Ot[4];
    #pragma unroll
    for (int hc = 0; hc < 4; ++hc) Ot[hc] = (f32x4){0.f, 0.f, 0.f, 0.f};
    float m = -INFINITY, lsum = 0.f;

    for (int kt = wv; kt <= adiag; kt += 4) {
        const int ktb = kt * 64;
        const unsigned short* ktile = kbase + (long long)ktb * H_DIM;

        // ---- QK^T: 8 MFMAs -> S^T for 64 keys x 16 q-rows ----
        f32x4 S[4];
        const f32x4 z = {0.f, 0.f, 0.f, 0.f};
        #pragma unroll
        for (int ks = 0; ks < 4; ++ks) {
            const unsigned short* krow = ktile + (16 * ks + l15) * H_DIM + 4 * g;
            s16x8 K0 = ld_frag(krow,      krow + 16);
            s16x8 K1 = ld_frag(krow + 32, krow + 48);
            f32x4 s0 = __builtin_amdgcn_mfma_f32_16x16x32_bf16(K0, Qf[0], z, 0, 0, 0);
            S[ks]    = __builtin_amdgcn_mfma_f32_16x16x32_bf16(K1, Qf[1], s0, 0, 0, 0);
        }

        if (kt == adiag) {   // causal mask (only the diagonal tile)
            const int qg = q0 + l15;
            #pragma unroll
            for (int ks = 0; ks < 4; ++ks) {
                #pragma unroll
                for (int r = 0; r < 4; ++r) {
                    const int key = ktb + 16 * ks + 4 * g + r;
                    S[ks][r] = (key > qg) ? -INFINITY : S[ks][r];
                }
            }
        }

        // ---- online softmax (state replicated across the 4 lane-groups of a q-row) ----
        float tm = S[0][0];
        #pragma unroll
        for (int ks = 0; ks < 4; ++ks) {
            #pragma unroll
            for (int r = 0; r < 4; ++r) tm = fmaxf(tm, S[ks][r]);
        }
        tm = fmaxf(tm, __shfl_xor(tm, 16));
        tm = fmaxf(tm, __shfl_xor(tm, 32));

        const float mn = fmaxf(m, tm);
        const float alpha = __expf(m - mn);

        float ps = 0.f;
        #pragma unroll
        for (int ks = 0; ks < 4; ++ks) {
            #pragma unroll
            for (int r = 0; r < 4; ++r) {
                const float p = __expf(S[ks][r] - mn);
                S[ks][r] = p;
                ps += p;
            }
        }
        ps += __shfl_xor(ps, 16);
        ps += __shfl_xor(ps, 32);
        lsum = lsum * alpha + ps;
        m = mn;

        #pragma unroll
        for (int hc = 0; hc < 4; ++hc) Ot[hc] *= alpha;

        // ---- P -> bf16 fragments (chained directly from S^T register layout) ----
        s16x8 Pf[2];
        #pragma unroll
        for (int kc = 0; kc < 2; ++kc) {
            #pragma unroll
            for (int j = 0; j < 8; ++j)
                Pf[kc][j] = (short)f2bf(S[2 * kc + (j >> 2)][j & 3]);
        }

        // ---- PV: 8 MFMAs, V^T fragments from global (L2-resident) ----
        const unsigned short* vtile = vbase + ktb;
        #pragma unroll
        for (int hc = 0; hc < 4; ++hc) {
            const unsigned short* vrow = vtile + (long long)(hc * 16 + l15) * T_SEQ + 4 * g;
            s16x8 V0 = ld_frag(vrow,      vrow + 16);
            s16x8 V1 = ld_frag(vrow + 32, vrow + 48);
            Ot[hc] = __builtin_amdgcn_mfma_f32_16x16x32_bf16(V0, Pf[0], Ot[hc], 0, 0, 0);
            Ot[hc] = __builtin_amdgcn_mfma_f32_16x16x32_bf16(V1, Pf[1], Ot[hc], 0, 0, 0);
        }
    }

    // ---- split-K merge across the block's 4 waves ----
    #pragma unroll
    for (int hc = 0; hc < 4; ++hc) {
        #pragma unroll
        for (int r = 0; r < 4; ++r)
            Osh[wv][hc * 16 + 4 * g + r][l15] = Ot[hc][r];
    }
    if (l < 16) { msh[wv][l] = m; lsh[wv][l] = lsum; }
    __syncthreads();

    float mstar = msh[0][l15];
    #pragma unroll
    for (int w = 1; w < 4; ++w) mstar = fmaxf(mstar, msh[w][l15]);
    float fw[4], lstar = 0.f;
    #pragma unroll
    for (int w = 0; w < 4; ++w) {
        fw[w] = __expf(msh[w][l15] - mstar);
        lstar += lsh[w][l15] * fw[w];
    }
    const float inv = 1.f / lstar;

    #pragma unroll
    for (int r = 0; r < 4; ++r) {
        const int h = wv * 16 + 4 * g + r;
        float acc = 0.f;
        #pragma unroll
        for (int w = 0; w < 4; ++w) acc += Osh[w][h][l15] * fw[w];
        out[((long long)b * T_SEQ + q0 + l15) * H_DIM + h] = acc * inv;
    }
}

extern "C" void kernel_launch(void* const* d_in, const int* in_sizes, int n_in,
                              void* d_out, int out_size, void* d_ws, size_t ws_size,
                              hipStream_t stream) {
    const float* x  = (const float*)d_in[0];
    const float* Wq = (const float*)d_in[1];
    const float* bq = (const float*)d_in[2];
    const float* Wk = (const float*)d_in[3];
    const float* bk = (const float*)d_in[4];
    const float* Wv = (const float*)d_in[5];
    const float* bv = (const float*)d_in[6];

    const long long rows = (long long)B_SZ * T_SEQ;        // 16384
    unsigned short* qbuf = (unsigned short*)d_ws;
    unsigned short* kbuf = qbuf + rows * H_DIM;
    unsigned short* vTb  = kbuf + rows * H_DIM;

    qkv_proj<<<dim3(rows / 16), dim3(256), 0, stream>>>(x, Wq, bq, Wk, bk, Wv, bv,
                                                        qbuf, kbuf, vTb);
    attn<<<dim3(B_SZ * NQ), dim3(256), 0, stream>>>(qbuf, kbuf, vTb, (float*)d_out);
}

// Round 3
// 164.717 us; speedup vs baseline: 6.8321x; 1.5517x over previous
//
#include <hip/hip_runtime.h>
#include <math.h>

#define B_SZ   4
#define T_SEQ  4096
#define E_DIM  512
#define H_DIM  64

typedef float f32x4 __attribute__((ext_vector_type(4)));
typedef short s16x4 __attribute__((ext_vector_type(4)));
typedef short s16x8 __attribute__((ext_vector_type(8)));

static __device__ __forceinline__ unsigned short f2bf(float f) {
    union { float f; unsigned int u; } c; c.f = f;
    return (unsigned short)((c.u + 0x7fffu + ((c.u >> 16) & 1u)) >> 16);
}

static __device__ __forceinline__ s16x8 ld_frag(const unsigned short* p0, const unsigned short* p1) {
    s16x4 a = *(const s16x4*)p0;
    s16x4 b = *(const s16x4*)p1;
    return __builtin_shufflevector(a, b, 0, 1, 2, 3, 4, 5, 6, 7);
}

static __device__ __forceinline__ s16x8 pack_frag_f32(const float* p0, const float* p1) {
    f32x4 a = *(const f32x4*)p0;
    f32x4 b = *(const f32x4*)p1;
    s16x8 r;
    #pragma unroll
    for (int j = 0; j < 4; ++j) { r[j] = (short)f2bf(a[j]); r[4 + j] = (short)f2bf(b[j]); }
    return r;
}

// ---------------- W -> bf16 W^T (concat q|k|v), scale folded into q cols ----------------
// Wt[col][k], col 0..191 (0-63 = 0.125*Wq, 64-127 = Wk, 128-191 = Wv), k 0..511.
__global__ __launch_bounds__(256) void wconv(
    const float* __restrict__ Wq, const float* __restrict__ Wk, const float* __restrict__ Wv,
    unsigned short* __restrict__ Wt)
{
    const int col = blockIdx.x;
    const int m = col >> 6, h = col & 63;
    const float* src = (m == 0) ? Wq : (m == 1) ? Wk : Wv;
    const float sc = (m == 0) ? 0.125f : 1.0f;
    const int kk = threadIdx.x * 2;
    unsigned int lo = f2bf(src[kk * H_DIM + h] * sc);
    unsigned int hi = f2bf(src[(kk + 1) * H_DIM + h] * sc);
    ((unsigned int*)Wt)[(col * E_DIM + kk) >> 1] = lo | (hi << 16);
}

// ---------------- QKV projection via MFMA ----------------
// grid 256 blocks x 256 thr; block = 64 rows; wave w = rows 16w..16w+15, all 192 cols.
// mfma(Wt_frag, x_frag): lane l reg r -> out[row=rowbase+l15][col=16nt+4g+r]
__global__ __launch_bounds__(256) void qkv_mfma(
    const float* __restrict__ x, const unsigned short* __restrict__ Wt,
    const float* __restrict__ bq, const float* __restrict__ bk, const float* __restrict__ bv,
    unsigned short* __restrict__ qo, unsigned short* __restrict__ ko,
    unsigned short* __restrict__ vTo)
{
    __shared__ unsigned short Wout[192][72];   // [col][row-in-block], stride 72 -> 16B-aligned rows

    const int t = threadIdx.x, wv = t >> 6, l = t & 63, l15 = l & 15, g = l >> 4;
    const long long row0 = (long long)blockIdx.x * 64;

    f32x4 acc[12];
    #pragma unroll
    for (int nt = 0; nt < 12; ++nt) acc[nt] = (f32x4){0.f, 0.f, 0.f, 0.f};

    const float* xr = x + (row0 + wv * 16 + l15) * E_DIM + 4 * g;
    for (int kc = 0; kc < E_DIM; kc += 32) {
        const s16x8 xf = pack_frag_f32(xr + kc, xr + kc + 16);
        #pragma unroll
        for (int nt = 0; nt < 12; ++nt) {
            const unsigned short* wr = Wt + (nt * 16 + l15) * E_DIM + kc + 4 * g;
            const s16x8 wf = ld_frag(wr, wr + 16);
            acc[nt] = __builtin_amdgcn_mfma_f32_16x16x32_bf16(wf, xf, acc[nt], 0, 0, 0);
        }
    }

    #pragma unroll
    for (int nt = 0; nt < 12; ++nt) {
        const float* bsrc = (nt < 4) ? bq : (nt < 8) ? bk : bv;
        const float bscale = (nt < 4) ? 0.125f : 1.0f;
        const f32x4 bb = *(const f32x4*)(bsrc + (nt & 3) * 16 + 4 * g);
        #pragma unroll
        for (int r = 0; r < 4; ++r)
            Wout[nt * 16 + 4 * g + r][wv * 16 + l15] = f2bf(acc[nt][r] + bb[r] * bscale);
    }
    __syncthreads();

    // q,k: row-major [row][h]
    {
        const int row = t >> 2, c0 = (t & 3) * 16;
        s16x8 v0, v1;
        #pragma unroll
        for (int i = 0; i < 8; ++i) { v0[i] = (short)Wout[c0 + i][row]; v1[i] = (short)Wout[c0 + 8 + i][row]; }
        *(s16x8*)(qo + (row0 + row) * H_DIM + c0) = v0;
        *(s16x8*)(qo + (row0 + row) * H_DIM + c0 + 8) = v1;
        #pragma unroll
        for (int i = 0; i < 8; ++i) { v0[i] = (short)Wout[64 + c0 + i][row]; v1[i] = (short)Wout[64 + c0 + 8 + i][row]; }
        *(s16x8*)(ko + (row0 + row) * H_DIM + c0) = v0;
        *(s16x8*)(ko + (row0 + row) * H_DIM + c0 + 8) = v1;
    }
    // v^T: [b*64+h][t]
    {
        const int h = t >> 2, tc = (t & 3) * 16;
        const int b = (int)(row0 >> 12), tloc = (int)(row0 & 4095);
        const s16x8 v0 = *(const s16x8*)&Wout[128 + h][tc];
        const s16x8 v1 = *(const s16x8*)&Wout[128 + h][tc + 8];
        *(s16x8*)(vTo + ((long long)(b * H_DIM + h)) * T_SEQ + tloc + tc) = v0;
        *(s16x8*)(vTo + ((long long)(b * H_DIM + h)) * T_SEQ + tloc + tc + 8) = v1;
    }
}

// ---------------- causal flash attention, bf16 MFMA, 32 q-rows/wave ----------------
// grid 512 blocks x 4 waves. Block = 32 q-rows; wave w does k-tiles kt ≡ w (mod 4).
// XCD remap: xcd = bid&7 owns batch (xcd>>1); per-XCD working set = 1 batch = L2-resident.
__global__ __launch_bounds__(256, 2) void attn(
    const unsigned short* __restrict__ qb,
    const unsigned short* __restrict__ kb,
    const unsigned short* __restrict__ vT,
    float* __restrict__ out)
{
    __shared__ float Osh[4][64][33];
    __shared__ float msh[4][32];
    __shared__ float lsh[4][32];

    const int t = threadIdx.x, wv = t >> 6, l = t & 63, l15 = l & 15, g = l >> 4;

    const int bid = blockIdx.x;
    const int xcd = bid & 7;
    const int b   = xcd >> 1;
    const int u   = bid >> 3;
    const int qi  = 127 - (2 * u + (xcd & 1));   // longest-first per XCD stream
    const int q0  = qi * 32;
    const int adiag = (q0 + 31) >> 6;

    const unsigned short* kbase = kb + (long long)b * T_SEQ * H_DIM;
    const unsigned short* vbase = vT + (long long)b * H_DIM * T_SEQ;

    s16x8 Qf[2][2];
    #pragma unroll
    for (int s = 0; s < 2; ++s) {
        const unsigned short* qrow = qb + ((long long)b * T_SEQ + q0 + 16 * s + l15) * H_DIM + 4 * g;
        Qf[s][0] = ld_frag(qrow, qrow + 16);
        Qf[s][1] = ld_frag(qrow + 32, qrow + 48);
    }

    f32x4 O[2][4];
    #pragma unroll
    for (int s = 0; s < 2; ++s)
        #pragma unroll
        for (int hc = 0; hc < 4; ++hc) O[s][hc] = (f32x4){0.f, 0.f, 0.f, 0.f};
    float m[2]   = {-INFINITY, -INFINITY};
    float lsm[2] = {0.f, 0.f};

    s16x8 Ka[4], Kc[4];
    #define LOAD_K(KT, A, C)                                                            \
        {                                                                               \
            const unsigned short* ktile_ = kbase + (long long)((KT) * 64) * H_DIM;      \
            _Pragma("unroll")                                                           \
            for (int ks = 0; ks < 4; ++ks) {                                            \
                const unsigned short* krow_ = ktile_ + (16 * ks + l15) * H_DIM + 4 * g; \
                (A)[ks] = ld_frag(krow_, krow_ + 16);                                   \
                (C)[ks] = ld_frag(krow_ + 32, krow_ + 48);                              \
            }                                                                           \
        }

    if (wv <= adiag) LOAD_K(wv, Ka, Kc);

    for (int kt = wv; kt <= adiag; kt += 4) {
        const int ktb = kt * 64;
        const f32x4 z = {0.f, 0.f, 0.f, 0.f};

        // ---- QK^T: 16 MFMAs (K frags shared across the 2 q-subtiles) ----
        f32x4 S[2][4];
        #pragma unroll
        for (int ks = 0; ks < 4; ++ks) {
            #pragma unroll
            for (int s = 0; s < 2; ++s) {
                f32x4 s0 = __builtin_amdgcn_mfma_f32_16x16x32_bf16(Ka[ks], Qf[s][0], z, 0, 0, 0);
                S[s][ks] = __builtin_amdgcn_mfma_f32_16x16x32_bf16(Kc[ks], Qf[s][1], s0, 0, 0, 0);
            }
        }

        // ---- V frags (independent of softmax -> issue early) ----
        s16x8 Va[4], Vc[4];
        #pragma unroll
        for (int hc = 0; hc < 4; ++hc) {
            const unsigned short* vrow = vbase + (long long)(hc * 16 + l15) * T_SEQ + ktb + 4 * g;
            Va[hc] = ld_frag(vrow, vrow + 16);
            Vc[hc] = ld_frag(vrow + 32, vrow + 48);
        }

        // ---- prefetch next K tile (clamped; dead on last iter) ----
        s16x8 Kna[4], Knc[4];
        {
            int ktn = kt + 4; if (ktn > adiag) ktn = adiag;
            LOAD_K(ktn, Kna, Knc);
        }

        if (kt == adiag) {   // causal mask, diagonal tile only
            #pragma unroll
            for (int s = 0; s < 2; ++s) {
                const int qg = q0 + 16 * s + l15;
                #pragma unroll
                for (int ks = 0; ks < 4; ++ks)
                    #pragma unroll
                    for (int r = 0; r < 4; ++r) {
                        const int key = ktb + 16 * ks + 4 * g + r;
                        S[s][ks][r] = (key > qg) ? -INFINITY : S[s][ks][r];
                    }
            }
        }

        // ---- online softmax + P fragments ----
        s16x8 Pf[2][2];
        #pragma unroll
        for (int s = 0; s < 2; ++s) {
            float tm = S[s][0][0];
            #pragma unroll
            for (int ks = 0; ks < 4; ++ks)
                #pragma unroll
                for (int r = 0; r < 4; ++r) tm = fmaxf(tm, S[s][ks][r]);
            tm = fmaxf(tm, __shfl_xor(tm, 16));
            tm = fmaxf(tm, __shfl_xor(tm, 32));
            const float mn = fmaxf(m[s], tm);
            const float alpha = __expf(m[s] - mn);
            float ps = 0.f;
            #pragma unroll
            for (int ks = 0; ks < 4; ++ks)
                #pragma unroll
                for (int r = 0; r < 4; ++r) {
                    const float p = __expf(S[s][ks][r] - mn);
                    S[s][ks][r] = p;
                    ps += p;
                }
            ps += __shfl_xor(ps, 16);
            ps += __shfl_xor(ps, 32);
            lsm[s] = lsm[s] * alpha + ps;
            m[s] = mn;
            #pragma unroll
            for (int hc = 0; hc < 4; ++hc) O[s][hc] *= alpha;
            #pragma unroll
            for (int kc = 0; kc < 2; ++kc)
                #pragma unroll
                for (int j = 0; j < 8; ++j)
                    Pf[s][kc][j] = (short)f2bf(S[s][2 * kc + (j >> 2)][j & 3]);
        }

        // ---- PV: 16 MFMAs (V frags shared across q-subtiles) ----
        #pragma unroll
        for (int hc = 0; hc < 4; ++hc) {
            #pragma unroll
            for (int s = 0; s < 2; ++s) {
                O[s][hc] = __builtin_amdgcn_mfma_f32_16x16x32_bf16(Va[hc], Pf[s][0], O[s][hc], 0, 0, 0);
                O[s][hc] = __builtin_amdgcn_mfma_f32_16x16x32_bf16(Vc[hc], Pf[s][1], O[s][hc], 0, 0, 0);
            }
        }

        #pragma unroll
        for (int ks = 0; ks < 4; ++ks) { Ka[ks] = Kna[ks]; Kc[ks] = Knc[ks]; }
    }
    #undef LOAD_K

    // ---- split-K merge ----
    #pragma unroll
    for (int s = 0; s < 2; ++s)
        #pragma unroll
        for (int hc = 0; hc < 4; ++hc)
            #pragma unroll
            for (int r = 0; r < 4; ++r)
                Osh[wv][hc * 16 + 4 * g + r][16 * s + l15] = O[s][hc][r];
    if (g == 0) {
        msh[wv][l15]      = m[0];
        msh[wv][16 + l15] = m[1];
        lsh[wv][l15]      = lsm[0];
        lsh[wv][16 + l15] = lsm[1];
    }
    __syncthreads();

    const int rl = t >> 3;          // 0..31 local q-row
    const int h0 = (t & 7) * 8;
    float mstar = msh[0][rl];
    #pragma unroll
    for (int w = 1; w < 4; ++w) mstar = fmaxf(mstar, msh[w][rl]);
    float fw[4], lstar = 0.f;
    #pragma unroll
    for (int w = 0; w < 4; ++w) {
        fw[w] = __expf(msh[w][rl] - mstar);
        lstar += lsh[w][rl] * fw[w];
    }
    const float inv = 1.f / lstar;

    f32x4 o0, o1;
    #pragma unroll
    for (int j = 0; j < 4; ++j) {
        float a0 = 0.f, a1 = 0.f;
        #pragma unroll
        for (int w = 0; w < 4; ++w) {
            a0 += Osh[w][h0 + j][rl] * fw[w];
            a1 += Osh[w][h0 + 4 + j][rl] * fw[w];
        }
        o0[j] = a0 * inv;
        o1[j] = a1 * inv;
    }
    float* op = out + ((long long)b * T_SEQ + q0 + rl) * H_DIM + h0;
    *(f32x4*)op = o0;
    *(f32x4*)(op + 4) = o1;
}

extern "C" void kernel_launch(void* const* d_in, const int* in_sizes, int n_in,
                              void* d_out, int out_size, void* d_ws, size_t ws_size,
                              hipStream_t stream) {
    const float* x  = (const float*)d_in[0];
    const float* Wq = (const float*)d_in[1];
    const float* bq = (const float*)d_in[2];
    const float* Wk = (const float*)d_in[3];
    const float* bk = (const float*)d_in[4];
    const float* Wv = (const float*)d_in[5];
    const float* bv = (const float*)d_in[6];

    const long long rows = (long long)B_SZ * T_SEQ;          // 16384
    unsigned short* qbuf = (unsigned short*)d_ws;
    unsigned short* kbuf = qbuf + rows * H_DIM;
    unsigned short* vTb  = kbuf + rows * H_DIM;
    unsigned short* Wt   = vTb + rows * H_DIM;               // [192][512] bf16

    wconv<<<dim3(192), dim3(256), 0, stream>>>(Wq, Wk, Wv, Wt);
    qkv_mfma<<<dim3(rows / 64), dim3(256), 0, stream>>>(x, Wt, bq, bk, bv, qbuf, kbuf, vTb);
    attn<<<dim3(B_SZ * (T_SEQ / 32)), dim3(256), 0, stream>>>(qbuf, kbuf, vTb, (float*)d_out);
}